// Round 1
// baseline (152.952 us; speedup 1.0000x reference)
//
#include <hip/hip_runtime.h>

// Trilinear interp of [64,64,64,64] fp32 volume at 200k points.
// R7: drop the LDS staging. R6 staged a 5^3 halo neighborhood (32 KB) per
// 4^3 bucket = 131 MB of reads for a 64 MB volume (2.05x over-fetch), then
// serialized stage -> vmcnt(0) barrier -> ~4 short compute iterations.
// Instead gather directly from global within the same bucket-swizzled
// schedule: each block's working set is ~32 KB (L1-sized), z-adjacent
// buckets on the same XCD reuse halos out of the 4 MB L2 (reuse window
// ~2 MB). Removes the barrier, the DMA drain, and the halo over-fetch.

#define NBUCK   4096          // 16^3 buckets of 4^3 voxels
#define CAP     128           // mean occupancy 48.8
#define OVCAP   8192

typedef float __attribute__((ext_vector_type(4))) fx4;

__device__ __forceinline__ float4 f4mul(float4 a, float s) {
    return make_float4(a.x * s, a.y * s, a.z * s, a.w * s);
}
__device__ __forceinline__ float4 f4fma(float4 a, float s, float4 acc) {
    return make_float4(fmaf(a.x, s, acc.x), fmaf(a.y, s, acc.y),
                       fmaf(a.z, s, acc.z), fmaf(a.w, s, acc.w));
}

__global__ __launch_bounds__(256) void scatter_kernel(
    const float* __restrict__ coords, int* __restrict__ counts,
    float4* __restrict__ buckets, float4* __restrict__ overflow, int n)
{
    int p = blockIdx.x * 256 + threadIdx.x;
    if (p >= n) return;
    float xs = coords[3 * p + 0] * 0.5f;
    float ys = coords[3 * p + 1] * 0.5f;
    float zs = coords[3 * p + 2] * 0.5f;
    int vx = (int)floorf(xs), vy = (int)floorf(ys), vz = (int)floorf(zs);
    int bucket = ((vx >> 2) << 8) | ((vy >> 2) << 4) | (vz >> 2);
    int slot = atomicAdd(&counts[bucket], 1);
    float4 v = make_float4(xs, ys, zs, __int_as_float(p));
    if (slot < CAP) {
        buckets[bucket * CAP + slot] = v;
    } else {
        int o = atomicAdd(&counts[NBUCK], 1);
        if (o < OVCAP) overflow[o] = v;
    }
}

__device__ __forceinline__ void lerp_store(
    const float4* __restrict__ imgv, float4 cs, int cvec,
    float* __restrict__ out)
{
    float x = cs.x, y = cs.y, z = cs.z;
    int p = __float_as_int(cs.w);

    float fx1 = floorf(x), fx2 = fminf(ceilf(x), 63.0f);
    float fy1 = floorf(y), fy2 = fminf(ceilf(y), 63.0f);
    float fz1 = floorf(z), fz2 = fminf(ceilf(z), 63.0f);

    int bx1 = ((int)fx1) << 12, bx2 = ((int)fx2) << 12;
    int by1 = ((int)fy1) << 6,  by2 = ((int)fy2) << 6;
    int iz1 = (int)fz1, iz2 = (int)fz2;

    float4 q111 = imgv[((bx1 + by1 + iz1) << 4) + cvec];
    float4 q211 = imgv[((bx2 + by1 + iz1) << 4) + cvec];
    float4 q121 = imgv[((bx1 + by2 + iz1) << 4) + cvec];
    float4 q221 = imgv[((bx2 + by2 + iz1) << 4) + cvec];
    float4 q112 = imgv[((bx1 + by1 + iz2) << 4) + cvec];
    float4 q212 = imgv[((bx2 + by1 + iz2) << 4) + cvec];
    float4 q122 = imgv[((bx1 + by2 + iz2) << 4) + cvec];
    float4 q222 = imgv[((bx2 + by2 + iz2) << 4) + cvec];

    float wx = x - fx1, wxc = fx2 - x;
    float wy = y - fy1, wyc = fy2 - y;
    float wz = z - fz1, wzc = fz2 - z;

    float4 ly1v = f4fma(f4fma(q221, wx, f4mul(q121, wxc)), wy,
                        f4mul(f4fma(q211, wx, f4mul(q111, wxc)), wyc));
    float4 ly2v = f4fma(f4fma(q222, wx, f4mul(q122, wxc)), wy,
                        f4mul(f4fma(q212, wx, f4mul(q112, wxc)), wyc));
    float4 res = f4fma(ly2v, wz, f4mul(ly1v, wzc));

    fx4 r; r.x = res.x; r.y = res.y; r.z = res.z; r.w = res.w;
    __builtin_nontemporal_store(r, (fx4*)out + (p << 4) + cvec);
}

__global__ __launch_bounds__(256) void gather_kernel(
    const float* __restrict__ img, const int* __restrict__ counts,
    const float4* __restrict__ buckets, const float4* __restrict__ overflow,
    float* __restrict__ out)
{
    const float4* __restrict__ imgv = (const float4*)img;
    int cvec = threadIdx.x & 15;
    int grp  = threadIdx.x >> 4;          // 0..15

    if (blockIdx.x < NBUCK) {
        // XCD chunk swizzle: 8 XCDs x 512 contiguous buckets each.
        // Buckets walk z fastest within an XCD's x-slab -> the 5^3 halo of
        // each bucket is reused out of L1 (same block) / L2 (z,y neighbors).
        int bucket = (blockIdx.x & 7) * 512 + (blockIdx.x >> 3);
        int cnt = min(counts[bucket], CAP);

        for (int i = grp; i < cnt; i += 16) {
            float4 cs = buckets[bucket * CAP + i];
            lerp_store(imgv, cs, cvec, out);
        }
    } else {
        // overflow points (normally zero): direct global gather
        int ob = blockIdx.x - NBUCK;            // 0..31
        int cnt = min(counts[NBUCK], OVCAP);
        for (int i = (ob << 4) + grp; i < cnt; i += 32 * 16) {
            float4 cs = overflow[i];
            lerp_store(imgv, cs, cvec, out);
        }
    }
}

// Fallback (R1 kernel) if workspace too small.
__global__ __launch_bounds__(256) void trilerp_kernel(
    const float* __restrict__ img, const float* __restrict__ coords,
    float* __restrict__ out, int n_points)
{
    int tid = blockIdx.x * 256 + threadIdx.x;
    int p = tid >> 4;
    if (p >= n_points) return;
    int cvec = tid & 15;

    float x = coords[3 * p + 0] * 0.5f;
    float y = coords[3 * p + 1] * 0.5f;
    float z = coords[3 * p + 2] * 0.5f;

    float4 cs = make_float4(x, y, z, __int_as_float(p));
    lerp_store((const float4*)img, cs, cvec, out);
}

extern "C" void kernel_launch(void* const* d_in, const int* in_sizes, int n_in,
                              void* d_out, int out_size, void* d_ws, size_t ws_size,
                              hipStream_t stream) {
    const float* img    = (const float*)d_in[0];   // [1,64,64,64,64]
    const float* coords = (const float*)d_in[1];   // [1,N,3]
    float* out = (float*)d_out;                    // [1,N,64]
    int n = in_sizes[1] / 3;

    size_t counts_bytes = 32768;                              // 4097 ints, padded
    size_t buckets_off  = counts_bytes;
    size_t buckets_bytes = (size_t)NBUCK * CAP * sizeof(float4);   // 8 MB
    size_t overflow_off = buckets_off + buckets_bytes;
    size_t need = overflow_off + (size_t)OVCAP * sizeof(float4);

    if (ws_size >= need) {
        int*    counts   = (int*)d_ws;
        float4* buckets  = (float4*)((char*)d_ws + buckets_off);
        float4* overflow = (float4*)((char*)d_ws + overflow_off);

        hipMemsetAsync(counts, 0, (NBUCK + 1) * sizeof(int), stream);
        int pgrid = (n + 255) / 256;
        scatter_kernel<<<pgrid, 256, 0, stream>>>(coords, counts, buckets, overflow, n);
        gather_kernel<<<NBUCK + 32, 256, 0, stream>>>(img, counts, buckets, overflow, out);
    } else {
        int threads = n * 16;
        int grid = (threads + 255) / 256;
        trilerp_kernel<<<grid, 256, 0, stream>>>(img, coords, out, n);
    }
}

// Round 2
// 144.581 us; speedup vs baseline: 1.0579x; 1.0579x over previous
//
#include <hip/hip_runtime.h>

// Trilinear interp of [64,64,64,64] fp32 volume at 200k points.
// R8: staged-LDS gather (R6 structure, the verified winner) + T3/T4-style
// software pipeline. 512 persistent blocks x 512 threads (2 blocks/CU),
// each owns 8 z-consecutive buckets. LDS double-buffer 2 x 32KB; per
// bucket each wave issues 4 global_load_lds chunks; counted
// s_waitcnt vmcnt(4) + raw s_barrier keep the next bucket's DMAs in
// flight across the barrier (never drain to 0 in steady state).
// R7 post-mortem: direct gather was latency-bound (25% HBM, VALU 15%);
// staging IS the latency hiding. z-chained buckets make halo re-reads
// L2 hits, so HBM fetch ~ compulsory volume.

#define NBUCK   4096          // 16^3 buckets of 4^3 voxels
#define CAP     128           // mean occupancy 48.8
#define OVCAP   8192
#define TILE_F4 2048          // 5^3 voxels * 16 float4 = 2000, padded to 2048
#define NGB     512           // gather blocks (8 buckets each)
#define NB_PER  8             // buckets per gather block

typedef float __attribute__((ext_vector_type(4))) fx4;

#define GLOBAL_AS __attribute__((address_space(1)))
#define LDS_AS    __attribute__((address_space(3)))

__device__ __forceinline__ void async_copy16(const float4* g, float4* l) {
    __builtin_amdgcn_global_load_lds(
        (const GLOBAL_AS unsigned int*)(const void*)g,
        (LDS_AS unsigned int*)(void*)l, 16, 0, 0);
}

__device__ __forceinline__ float4 f4mul(float4 a, float s) {
    return make_float4(a.x * s, a.y * s, a.z * s, a.w * s);
}
__device__ __forceinline__ float4 f4fma(float4 a, float s, float4 acc) {
    return make_float4(fmaf(a.x, s, acc.x), fmaf(a.y, s, acc.y),
                       fmaf(a.z, s, acc.z), fmaf(a.w, s, acc.w));
}

__global__ __launch_bounds__(256) void scatter_kernel(
    const float* __restrict__ coords, int* __restrict__ counts,
    float4* __restrict__ buckets, float4* __restrict__ overflow, int n)
{
    int p = blockIdx.x * 256 + threadIdx.x;
    if (p >= n) return;
    float xs = coords[3 * p + 0] * 0.5f;
    float ys = coords[3 * p + 1] * 0.5f;
    float zs = coords[3 * p + 2] * 0.5f;
    int vx = (int)floorf(xs), vy = (int)floorf(ys), vz = (int)floorf(zs);
    int bucket = ((vx >> 2) << 8) | ((vy >> 2) << 4) | (vz >> 2);
    int slot = atomicAdd(&counts[bucket], 1);
    float4 v = make_float4(xs, ys, zs, __int_as_float(p));
    if (slot < CAP) {
        buckets[bucket * CAP + slot] = v;
    } else {
        int o = atomicAdd(&counts[NBUCK], 1);
        if (o < OVCAP) overflow[o] = v;
    }
}

// Stage one bucket's 5x5x5 halo neighborhood (2048 float4 incl. pad) into
// dst. 8 waves x 4 chunks x 64 lanes x 16B = 32 KB. Fire-and-forget.
__device__ __forceinline__ void stage_bucket(
    const float4* __restrict__ imgv, int bucket, float4* dst,
    int wv, int lane)
{
    int bx0 = (bucket >> 8) << 2;
    int by0 = ((bucket >> 4) & 15) << 2;
    int bz0 = (bucket & 15) << 2;
    #pragma unroll
    for (int c = 0; c < 4; c++) {
        int chunk = (wv << 2) + c;           // 0..31
        int f = chunk * 64 + lane;           // 0..2047
        int tv = min(f >> 4, 124);           // voxel 0..124 (pad clamps)
        int ch = f & 15;
        int lx = tv / 25;
        int rem = tv - lx * 25;
        int ly = rem / 5;
        int lz = rem - ly * 5;
        int gx = min(bx0 + lx, 63);
        int gy = min(by0 + ly, 63);
        int gz = min(bz0 + lz, 63);
        const float4* src = &imgv[(((((gx << 6) + gy) << 6) + gz) << 4) + ch];
        async_copy16(src, dst + chunk * 64); // HW adds lane*16B
    }
}

__device__ __forceinline__ void lerp_global_store(
    const float4* __restrict__ imgv, float4 cs, int cvec,
    float* __restrict__ out)
{
    float x = cs.x, y = cs.y, z = cs.z;
    int p = __float_as_int(cs.w);

    float fx1 = floorf(x), fx2 = fminf(ceilf(x), 63.0f);
    float fy1 = floorf(y), fy2 = fminf(ceilf(y), 63.0f);
    float fz1 = floorf(z), fz2 = fminf(ceilf(z), 63.0f);

    int bx1 = ((int)fx1) << 12, bx2 = ((int)fx2) << 12;
    int by1 = ((int)fy1) << 6,  by2 = ((int)fy2) << 6;
    int iz1 = (int)fz1, iz2 = (int)fz2;

    float4 q111 = imgv[((bx1 + by1 + iz1) << 4) + cvec];
    float4 q211 = imgv[((bx2 + by1 + iz1) << 4) + cvec];
    float4 q121 = imgv[((bx1 + by2 + iz1) << 4) + cvec];
    float4 q221 = imgv[((bx2 + by2 + iz1) << 4) + cvec];
    float4 q112 = imgv[((bx1 + by1 + iz2) << 4) + cvec];
    float4 q212 = imgv[((bx2 + by1 + iz2) << 4) + cvec];
    float4 q122 = imgv[((bx1 + by2 + iz2) << 4) + cvec];
    float4 q222 = imgv[((bx2 + by2 + iz2) << 4) + cvec];

    float wx = x - fx1, wxc = fx2 - x;
    float wy = y - fy1, wyc = fy2 - y;
    float wz = z - fz1, wzc = fz2 - z;

    float4 ly1v = f4fma(f4fma(q221, wx, f4mul(q121, wxc)), wy,
                        f4mul(f4fma(q211, wx, f4mul(q111, wxc)), wyc));
    float4 ly2v = f4fma(f4fma(q222, wx, f4mul(q122, wxc)), wy,
                        f4mul(f4fma(q212, wx, f4mul(q112, wxc)), wyc));
    float4 res = f4fma(ly2v, wz, f4mul(ly1v, wzc));

    fx4 r; r.x = res.x; r.y = res.y; r.z = res.z; r.w = res.w;
    __builtin_nontemporal_store(r, (fx4*)out + (p << 4) + cvec);
}

__global__ __launch_bounds__(512) void gather_kernel(
    const float* __restrict__ img, const int* __restrict__ counts,
    const float4* __restrict__ buckets, const float4* __restrict__ overflow,
    float* __restrict__ out)
{
    const float4* __restrict__ imgv = (const float4*)img;
    int cvec = threadIdx.x & 15;
    int grp  = threadIdx.x >> 4;          // 0..31

    if (blockIdx.x < NGB) {
        __shared__ float4 tile[2][TILE_F4];   // 64 KB double buffer
        int wv   = threadIdx.x >> 6;          // wave 0..7
        int lane = threadIdx.x & 63;
        // XCD swizzle on blocks; each block owns 8 z-consecutive buckets
        // so successive halos are L2-resident re-reads.
        int bbase = (blockIdx.x & 7) * 512 + (blockIdx.x >> 3) * NB_PER;

        // prologue: stage bucket 0 (4 chunks/wave in flight)
        stage_bucket(imgv, bbase, tile[0], wv, lane);

        for (int i = 0; i < NB_PER; ++i) {
            float4* cur = tile[i & 1];
            if (i + 1 < NB_PER) {
                // issue next bucket's DMAs into the other buffer, then wait
                // until only those 4 remain -> bucket i's chunks (and any
                // older compute vmem) have landed. Never vmcnt(0) here.
                stage_bucket(imgv, bbase + i + 1, tile[(i + 1) & 1], wv, lane);
                asm volatile("s_waitcnt vmcnt(4)" ::: "memory");
            } else {
                asm volatile("s_waitcnt vmcnt(0)" ::: "memory");
            }
            __builtin_amdgcn_s_barrier();
            asm volatile("" ::: "memory");

            int bucket = bbase + i;
            int bx0 = (bucket >> 8) << 2;
            int by0 = ((bucket >> 4) & 15) << 2;
            int bz0 = (bucket & 15) << 2;
            int cnt = min(counts[bucket], CAP);

            for (int t = grp; t < cnt; t += 32) {
                float4 cs = buckets[bucket * CAP + t];
                float x = cs.x, y = cs.y, z = cs.z;
                int p = __float_as_int(cs.w);

                float fx1 = floorf(x), fx2 = fminf(ceilf(x), 63.0f);
                float fy1 = floorf(y), fy2 = fminf(ceilf(y), 63.0f);
                float fz1 = floorf(z), fz2 = fminf(ceilf(z), 63.0f);

                int lx1 = (int)fx1 - bx0, lx2 = (int)fx2 - bx0;   // 0..4
                int ly1 = (int)fy1 - by0, ly2 = (int)fy2 - by0;
                int lz1 = (int)fz1 - bz0, lz2 = (int)fz2 - bz0;
                int ax1 = lx1 * 25, ax2 = lx2 * 25;
                int ay1 = ly1 * 5,  ay2 = ly2 * 5;

                float4 q111 = cur[((ax1 + ay1 + lz1) << 4) + cvec];
                float4 q211 = cur[((ax2 + ay1 + lz1) << 4) + cvec];
                float4 q121 = cur[((ax1 + ay2 + lz1) << 4) + cvec];
                float4 q221 = cur[((ax2 + ay2 + lz1) << 4) + cvec];
                float4 q112 = cur[((ax1 + ay1 + lz2) << 4) + cvec];
                float4 q212 = cur[((ax2 + ay1 + lz2) << 4) + cvec];
                float4 q122 = cur[((ax1 + ay2 + lz2) << 4) + cvec];
                float4 q222 = cur[((ax2 + ay2 + lz2) << 4) + cvec];

                float wx = x - fx1, wxc = fx2 - x;
                float wy = y - fy1, wyc = fy2 - y;
                float wz = z - fz1, wzc = fz2 - z;

                float4 ly1v = f4fma(f4fma(q221, wx, f4mul(q121, wxc)), wy,
                                    f4mul(f4fma(q211, wx, f4mul(q111, wxc)), wyc));
                float4 ly2v = f4fma(f4fma(q222, wx, f4mul(q122, wxc)), wy,
                                    f4mul(f4fma(q212, wx, f4mul(q112, wxc)), wyc));
                float4 res = f4fma(ly2v, wz, f4mul(ly1v, wzc));

                fx4 r; r.x = res.x; r.y = res.y; r.z = res.z; r.w = res.w;
                __builtin_nontemporal_store(r, (fx4*)out + (p << 4) + cvec);
            }
            // all waves done reading cur before next iter's DMAs overwrite it
            asm volatile("" ::: "memory");
            __builtin_amdgcn_s_barrier();
        }
    } else {
        // overflow points (normally zero): direct global gather
        int ob = blockIdx.x - NGB;            // 0..31
        int cnt = min(counts[NBUCK], OVCAP);
        for (int i = (ob << 5) + grp; i < cnt; i += 32 * 32) {
            float4 cs = overflow[i];
            lerp_global_store(imgv, cs, cvec, out);
        }
    }
}

// Fallback (R1 kernel) if workspace too small.
__global__ __launch_bounds__(256) void trilerp_kernel(
    const float* __restrict__ img, const float* __restrict__ coords,
    float* __restrict__ out, int n_points)
{
    int tid = blockIdx.x * 256 + threadIdx.x;
    int p = tid >> 4;
    if (p >= n_points) return;
    int cvec = tid & 15;

    float x = coords[3 * p + 0] * 0.5f;
    float y = coords[3 * p + 1] * 0.5f;
    float z = coords[3 * p + 2] * 0.5f;

    float4 cs = make_float4(x, y, z, __int_as_float(p));
    lerp_global_store((const float4*)img, cs, cvec, out);
}

extern "C" void kernel_launch(void* const* d_in, const int* in_sizes, int n_in,
                              void* d_out, int out_size, void* d_ws, size_t ws_size,
                              hipStream_t stream) {
    const float* img    = (const float*)d_in[0];   // [1,64,64,64,64]
    const float* coords = (const float*)d_in[1];   // [1,N,3]
    float* out = (float*)d_out;                    // [1,N,64]
    int n = in_sizes[1] / 3;

    size_t counts_bytes = 32768;                              // 4097 ints, padded
    size_t buckets_off  = counts_bytes;
    size_t buckets_bytes = (size_t)NBUCK * CAP * sizeof(float4);   // 8 MB
    size_t overflow_off = buckets_off + buckets_bytes;
    size_t need = overflow_off + (size_t)OVCAP * sizeof(float4);

    if (ws_size >= need) {
        int*    counts   = (int*)d_ws;
        float4* buckets  = (float4*)((char*)d_ws + buckets_off);
        float4* overflow = (float4*)((char*)d_ws + overflow_off);

        hipMemsetAsync(counts, 0, (NBUCK + 1) * sizeof(int), stream);
        int pgrid = (n + 255) / 256;
        scatter_kernel<<<pgrid, 256, 0, stream>>>(coords, counts, buckets, overflow, n);
        gather_kernel<<<NGB + 32, 512, 0, stream>>>(img, counts, buckets, overflow, out);
    } else {
        int threads = n * 16;
        int grid = (threads + 255) / 256;
        trilerp_kernel<<<grid, 256, 0, stream>>>(img, coords, out, n);
    }
}

// Round 3
// 139.706 us; speedup vs baseline: 1.0948x; 1.0349x over previous
//
#include <hip/hip_runtime.h>

// Trilinear interp of [64,64,64,64] fp32 volume at 200k points.
// R9: R6's high-parallelism staged structure (4096 blocks, one 4^3 bucket
// + 5^3 halo tile each, async global->LDS DMA) with latency surgery:
//  - 512 threads/block (32 point-groups) -> 2 compute iters at mean
//    occupancy; 32 KB LDS -> 4 blocks/CU = 32 waves/CU (full occupancy).
//  - counts + point-list prefetched BEFORE the DMA chunks are issued, so
//    the compiler's first-use wait is vmcnt(4) (points done, DMAs still in
//    flight) and index/weight setup overlaps the DMA; post-barrier path is
//    pure LDS+FMA+store (no global loads for cnt<=64, 98.6% of buckets).
//  - two-plane q evaluation to keep VGPR under the 64-reg / 8-wave budget.
// R8 post-mortem: 2-deep bucket pipeline was cancelled by lost residency
// (2 blocks/CU vs 4-5); parallelism + shorter critical path wins here.

#define NBUCK   4096          // 16^3 buckets of 4^3 voxels
#define CAP     128           // mean occupancy 48.8
#define OVCAP   8192
#define TILE_F4 2048          // 5^3 voxels * 16 float4 = 2000, padded to 2048

typedef float __attribute__((ext_vector_type(4))) fx4;

#define GLOBAL_AS __attribute__((address_space(1)))
#define LDS_AS    __attribute__((address_space(3)))

__device__ __forceinline__ void async_copy16(const float4* g, float4* l) {
    __builtin_amdgcn_global_load_lds(
        (const GLOBAL_AS unsigned int*)(const void*)g,
        (LDS_AS unsigned int*)(void*)l, 16, 0, 0);
}

__device__ __forceinline__ float4 f4mul(float4 a, float s) {
    return make_float4(a.x * s, a.y * s, a.z * s, a.w * s);
}
__device__ __forceinline__ float4 f4fma(float4 a, float s, float4 acc) {
    return make_float4(fmaf(a.x, s, acc.x), fmaf(a.y, s, acc.y),
                       fmaf(a.z, s, acc.z), fmaf(a.w, s, acc.w));
}

__global__ __launch_bounds__(256) void scatter_kernel(
    const float* __restrict__ coords, int* __restrict__ counts,
    float4* __restrict__ buckets, float4* __restrict__ overflow, int n)
{
    int p = blockIdx.x * 256 + threadIdx.x;
    if (p >= n) return;
    float xs = coords[3 * p + 0] * 0.5f;
    float ys = coords[3 * p + 1] * 0.5f;
    float zs = coords[3 * p + 2] * 0.5f;
    int vx = (int)floorf(xs), vy = (int)floorf(ys), vz = (int)floorf(zs);
    int bucket = ((vx >> 2) << 8) | ((vy >> 2) << 4) | (vz >> 2);
    int slot = atomicAdd(&counts[bucket], 1);
    float4 v = make_float4(xs, ys, zs, __int_as_float(p));
    if (slot < CAP) {
        buckets[bucket * CAP + slot] = v;
    } else {
        int o = atomicAdd(&counts[NBUCK], 1);
        if (o < OVCAP) overflow[o] = v;
    }
}

// Pure-LDS trilinear lerp for one point (cs holds bucket-local coords in
// .x/.y/.z and the point id bit-cast in .w). Two-plane evaluation keeps
// only 4 q registers live at a time.
__device__ __forceinline__ void lerp_lds(
    const float4* __restrict__ cur, float4 cs,
    int bx0, int by0, int bz0, int cvec, float* __restrict__ out)
{
    float x = cs.x, y = cs.y, z = cs.z;
    int p = __float_as_int(cs.w);

    float fx1 = floorf(x), fx2 = fminf(ceilf(x), 63.0f);
    float fy1 = floorf(y), fy2 = fminf(ceilf(y), 63.0f);
    float fz1 = floorf(z), fz2 = fminf(ceilf(z), 63.0f);

    int ax1 = ((int)fx1 - bx0) * 25, ax2 = ((int)fx2 - bx0) * 25;
    int ay1 = ((int)fy1 - by0) * 5,  ay2 = ((int)fy2 - by0) * 5;
    int lz1 = (int)fz1 - bz0,        lz2 = (int)fz2 - bz0;

    float wx = x - fx1, wxc = fx2 - x;
    float wy = y - fy1, wyc = fy2 - y;
    float wz = z - fz1, wzc = fz2 - z;

    // z1 plane
    float4 q11 = cur[((ax1 + ay1 + lz1) << 4) + cvec];
    float4 q21 = cur[((ax2 + ay1 + lz1) << 4) + cvec];
    float4 q12 = cur[((ax1 + ay2 + lz1) << 4) + cvec];
    float4 q22 = cur[((ax2 + ay2 + lz1) << 4) + cvec];
    float4 ly1v = f4fma(f4fma(q22, wx, f4mul(q12, wxc)), wy,
                        f4mul(f4fma(q21, wx, f4mul(q11, wxc)), wyc));
    // z2 plane
    q11 = cur[((ax1 + ay1 + lz2) << 4) + cvec];
    q21 = cur[((ax2 + ay1 + lz2) << 4) + cvec];
    q12 = cur[((ax1 + ay2 + lz2) << 4) + cvec];
    q22 = cur[((ax2 + ay2 + lz2) << 4) + cvec];
    float4 ly2v = f4fma(f4fma(q22, wx, f4mul(q12, wxc)), wy,
                        f4mul(f4fma(q21, wx, f4mul(q11, wxc)), wyc));

    float4 res = f4fma(ly2v, wz, f4mul(ly1v, wzc));
    fx4 r; r.x = res.x; r.y = res.y; r.z = res.z; r.w = res.w;
    __builtin_nontemporal_store(r, (fx4*)out + (p << 4) + cvec);
}

__device__ __forceinline__ void lerp_global_store(
    const float4* __restrict__ imgv, float4 cs, int cvec,
    float* __restrict__ out)
{
    float x = cs.x, y = cs.y, z = cs.z;
    int p = __float_as_int(cs.w);

    float fx1 = floorf(x), fx2 = fminf(ceilf(x), 63.0f);
    float fy1 = floorf(y), fy2 = fminf(ceilf(y), 63.0f);
    float fz1 = floorf(z), fz2 = fminf(ceilf(z), 63.0f);

    int bx1 = ((int)fx1) << 12, bx2 = ((int)fx2) << 12;
    int by1 = ((int)fy1) << 6,  by2 = ((int)fy2) << 6;
    int iz1 = (int)fz1, iz2 = (int)fz2;

    float wx = x - fx1, wxc = fx2 - x;
    float wy = y - fy1, wyc = fy2 - y;
    float wz = z - fz1, wzc = fz2 - z;

    float4 q11 = imgv[((bx1 + by1 + iz1) << 4) + cvec];
    float4 q21 = imgv[((bx2 + by1 + iz1) << 4) + cvec];
    float4 q12 = imgv[((bx1 + by2 + iz1) << 4) + cvec];
    float4 q22 = imgv[((bx2 + by2 + iz1) << 4) + cvec];
    float4 ly1v = f4fma(f4fma(q22, wx, f4mul(q12, wxc)), wy,
                        f4mul(f4fma(q21, wx, f4mul(q11, wxc)), wyc));
    q11 = imgv[((bx1 + by1 + iz2) << 4) + cvec];
    q21 = imgv[((bx2 + by1 + iz2) << 4) + cvec];
    q12 = imgv[((bx1 + by2 + iz2) << 4) + cvec];
    q22 = imgv[((bx2 + by2 + iz2) << 4) + cvec];
    float4 ly2v = f4fma(f4fma(q22, wx, f4mul(q12, wxc)), wy,
                        f4mul(f4fma(q21, wx, f4mul(q11, wxc)), wyc));

    float4 res = f4fma(ly2v, wz, f4mul(ly1v, wzc));
    fx4 r; r.x = res.x; r.y = res.y; r.z = res.z; r.w = res.w;
    __builtin_nontemporal_store(r, (fx4*)out + (p << 4) + cvec);
}

__global__ __launch_bounds__(512, 8) void gather_kernel(
    const float* __restrict__ img, const int* __restrict__ counts,
    const float4* __restrict__ buckets, const float4* __restrict__ overflow,
    float* __restrict__ out)
{
    const float4* __restrict__ imgv = (const float4*)img;
    int cvec = threadIdx.x & 15;
    int grp  = threadIdx.x >> 4;          // 0..31

    if (blockIdx.x < NBUCK) {
        __shared__ float4 tile[TILE_F4];   // 32 KB single buffer
        int wv   = threadIdx.x >> 6;       // wave 0..7
        int lane = threadIdx.x & 63;
        // XCD chunk swizzle: 8 XCDs x 512 contiguous buckets, z-fastest ->
        // concurrent blocks on one XCD are z-neighbors, halo re-reads L2-hit.
        int bucket = (blockIdx.x & 7) * 512 + (blockIdx.x >> 3);
        int bx0 = (bucket >> 8) << 2;
        int by0 = ((bucket >> 4) & 15) << 2;
        int bz0 = (bucket & 15) << 2;

        // --- prefetch (oldest vmem first): counts + 2 points per group ---
        int cnt = counts[bucket];                       // uniform
        float4 cs0 = buckets[bucket * CAP + grp];       // always in-bounds
        float4 cs1 = buckets[bucket * CAP + grp + 32];  // (CAP=128)

        // --- stage 5^3 halo: 8 waves x 4 chunks x 64 lanes x 16B = 32 KB ---
        #pragma unroll
        for (int c = 0; c < 4; c++) {
            int chunk = (wv << 2) + c;           // 0..31
            int f = chunk * 64 + lane;           // 0..2047
            int tv = min(f >> 4, 124);           // voxel 0..124 (pad clamps)
            int ch = f & 15;
            int lx = tv / 25;
            int rem = tv - lx * 25;
            int ly = rem / 5;
            int lz = rem - ly * 5;
            int gx = min(bx0 + lx, 63);
            int gy = min(by0 + ly, 63);
            int gz = min(bz0 + lz, 63);
            const float4* src = &imgv[(((((gx << 6) + gy) << 6) + gz) << 4) + ch];
            async_copy16(src, &tile[chunk * 64]);   // HW adds lane*16B
        }
        cnt = min(cnt, CAP);

        // First use of cs0/cs1 is below the barrier; the compiler's wait for
        // them is vmcnt(4) (DMAs are newer), so any pre-barrier setup and the
        // other waves' staging overlap the point-load latency.
        __syncthreads();   // vmcnt(0): all DMAs landed

        if (grp < cnt)      lerp_lds(tile, cs0, bx0, by0, bz0, cvec, out);
        if (grp + 32 < cnt) lerp_lds(tile, cs1, bx0, by0, bz0, cvec, out);
        // residual (cnt > 64): ~1.4% of buckets
        for (int t = grp + 64; t < cnt; t += 32) {
            float4 cs = buckets[bucket * CAP + t];
            lerp_lds(tile, cs, bx0, by0, bz0, cvec, out);
        }
    } else {
        // overflow points (normally zero): direct global gather
        int ob = blockIdx.x - NBUCK;            // 0..31
        int cnt = min(counts[NBUCK], OVCAP);
        for (int i = (ob << 5) + grp; i < cnt; i += 32 * 32) {
            float4 cs = overflow[i];
            lerp_global_store(imgv, cs, cvec, out);
        }
    }
}

// Fallback (R1 kernel) if workspace too small.
__global__ __launch_bounds__(256) void trilerp_kernel(
    const float* __restrict__ img, const float* __restrict__ coords,
    float* __restrict__ out, int n_points)
{
    int tid = blockIdx.x * 256 + threadIdx.x;
    int p = tid >> 4;
    if (p >= n_points) return;
    int cvec = tid & 15;

    float x = coords[3 * p + 0] * 0.5f;
    float y = coords[3 * p + 1] * 0.5f;
    float z = coords[3 * p + 2] * 0.5f;

    float4 cs = make_float4(x, y, z, __int_as_float(p));
    lerp_global_store((const float4*)img, cs, cvec, out);
}

extern "C" void kernel_launch(void* const* d_in, const int* in_sizes, int n_in,
                              void* d_out, int out_size, void* d_ws, size_t ws_size,
                              hipStream_t stream) {
    const float* img    = (const float*)d_in[0];   // [1,64,64,64,64]
    const float* coords = (const float*)d_in[1];   // [1,N,3]
    float* out = (float*)d_out;                    // [1,N,64]
    int n = in_sizes[1] / 3;

    size_t counts_bytes = 32768;                              // 4097 ints, padded
    size_t buckets_off  = counts_bytes;
    size_t buckets_bytes = (size_t)NBUCK * CAP * sizeof(float4);   // 8 MB
    size_t overflow_off = buckets_off + buckets_bytes;
    size_t need = overflow_off + (size_t)OVCAP * sizeof(float4);

    if (ws_size >= need) {
        int*    counts   = (int*)d_ws;
        float4* buckets  = (float4*)((char*)d_ws + buckets_off);
        float4* overflow = (float4*)((char*)d_ws + overflow_off);

        hipMemsetAsync(counts, 0, (NBUCK + 1) * sizeof(int), stream);
        int pgrid = (n + 255) / 256;
        scatter_kernel<<<pgrid, 256, 0, stream>>>(coords, counts, buckets, overflow, n);
        gather_kernel<<<NBUCK + 32, 512, 0, stream>>>(img, counts, buckets, overflow, out);
    } else {
        int threads = n * 16;
        int grid = (threads + 255) / 256;
        trilerp_kernel<<<grid, 256, 0, stream>>>(img, coords, out, n);
    }
}